// Round 1
// baseline (388.562 us; speedup 1.0000x reference)
//
#include <hip/hip_runtime.h>
#include <hip/hip_bf16.h>

// Router: r[b,e] = || weights[e] @ x[b] ||_2
//   x: [8192, 4096] f32, weights: [16, 64, 4096] f32 -> out: [8192, 16] f32
//
// Strategy: fp32 -> bf16 hi/lo split, interleaved along K (K'=8192), single
// bf16 MFMA GEMM (permutation-invariant k mapping makes the interleave legal),
// fused per-expert squared-reduction epilogue (each wave's 64x64 C-quadrant is
// exactly one expert's 64 k-columns).

constexpr int Bdim = 8192;
constexpr int Ddim = 4096;
constexpr int Edim = 16;
constexpr int Kr   = 64;
constexpr int Ndim = Edim * Kr;     // 1024
constexpr int Kp   = 2 * Ddim;      // 8192 (hi/lo interleaved)

typedef __bf16 v8bf __attribute__((ext_vector_type(8)));
typedef float  v4f  __attribute__((ext_vector_type(4)));

// ---------------------------------------------------------------------------
// fp32 -> interleaved (hi, lo) bf16 pairs.  out[2i] = bf16_rne(in[i]),
// out[2i+1] = bf16_rne(in[i] - (float)out[2i]).  (hi+lo)·(hi+lo) expansion in
// the GEMM recovers fp32-accurate products (lo·lo included, harmless).
// ---------------------------------------------------------------------------
__global__ void cvt_hilo(const float* __restrict__ in, __bf16* __restrict__ out,
                         int n4) {
  int i = blockIdx.x * blockDim.x + threadIdx.x;
  int stride = gridDim.x * blockDim.x;
  for (; i < n4; i += stride) {
    float4 f = ((const float4*)in)[i];
    float v[4] = {f.x, f.y, f.z, f.w};
    v8bf o;
#pragma unroll
    for (int j = 0; j < 4; ++j) {
      __bf16 h = (__bf16)v[j];
      float  r = v[j] - (float)h;
      o[2 * j]     = h;
      o[2 * j + 1] = (__bf16)r;
    }
    *(v8bf*)(out + (size_t)i * 8) = o;
  }
}

// ---------------------------------------------------------------------------
// async global->LDS, 16B per lane; LDS dest is wave-uniform base + lane*16.
// ---------------------------------------------------------------------------
__device__ __forceinline__ void gload_lds16(const void* gsrc, void* ldst) {
  __builtin_amdgcn_global_load_lds(
      (const __attribute__((address_space(1))) unsigned int*)gsrc,
      (__attribute__((address_space(3))) unsigned int*)ldst, 16, 0, 0);
}

// ---------------------------------------------------------------------------
// GEMM + fused router epilogue.  m97 structure: 128x128 tile, BK=64, 4 waves
// (2x2), single LDS buffer, 2 barriers per K-step, global_load_lds width 16.
// LDS 16B-slot XOR swizzle (slot ^= row&7) applied on the READ side; the
// global SOURCE address is pre-swizzled so the linear global_load_lds dest
// lands each chunk where the read expects it (both-sides-or-neither, rule 21).
// ---------------------------------------------------------------------------
__global__ __launch_bounds__(256, 2)
void gemm_router(const __bf16* __restrict__ Xp,  // [8192][8192]
                 const __bf16* __restrict__ Wp,  // [1024][8192]
                 float* __restrict__ out) {      // [8192][16]
  __shared__ __bf16 As[128 * 64];  // 16 KB, row stride 128 B (8 slots x 16 B)
  __shared__ __bf16 Bs[128 * 64];  // 16 KB

  const int bid = blockIdx.x;       // 512 blocks: n fastest -> XCD = bn
  const int bm = bid >> 3;          // 0..63
  const int bn = bid & 7;           // 0..7
  const int tid  = threadIdx.x;
  const int lane = tid & 63;
  const int wid  = tid >> 6;        // 4 waves
  const int wr   = wid >> 1;        // wave row (0..1) -> 64 rows
  const int wc   = wid & 1;         // wave col (0..1) -> 64 cols = 1 expert
  const int l15  = lane & 15;
  const int lg   = lane >> 4;       // 16-lane group = k-group

  v4f acc[4][4] = {};               // 64 VGPRs accumulator

  // --- staging addresses (fixed per thread; add k0 each step) ---
  // chunk c: wave covers LDS rows [wid*32 + c*8, +8), lane -> (row=lane>>3,
  // slot=lane&7).  Source k-slot = slot ^ (row&7)  (row&7 == lane>>3 here).
  const int lr = lane >> 3;
  const int ls = lane & 7;
  const int ss = ls ^ lr;           // swizzled source slot
  const __bf16* pA[4];
  const __bf16* pB[4];
  char* ldsA[4];
  char* ldsB[4];
#pragma unroll
  for (int c = 0; c < 4; ++c) {
    int row = wid * 32 + c * 8 + lr;
    pA[c] = Xp + (size_t)(bm * 128 + row) * Kp + ss * 8;
    pB[c] = Wp + (size_t)(bn * 128 + row) * Kp + ss * 8;
    ldsA[c] = (char*)As + (wid * 4 + c) * 1024;
    ldsB[c] = (char*)Bs + (wid * 4 + c) * 1024;
  }

  for (int k0 = 0; k0 < Kp; k0 += 64) {
    __syncthreads();                 // prev iter done reading LDS
#pragma unroll
    for (int c = 0; c < 4; ++c) gload_lds16(pA[c] + k0, ldsA[c]);
#pragma unroll
    for (int c = 0; c < 4; ++c) gload_lds16(pB[c] + k0, ldsB[c]);
    __syncthreads();                 // compiler drains vmcnt before barrier

#pragma unroll
    for (int kk = 0; kk < 2; ++kk) {
      const int slot = ((kk << 2) + lg) ^ (lane & 7);
      v8bf a[4], b[4];
#pragma unroll
      for (int mf = 0; mf < 4; ++mf) {
        int row = (wr << 6) + (mf << 4) + l15;
        a[mf] = *(const v8bf*)((const char*)As + row * 128 + slot * 16);
      }
#pragma unroll
      for (int nf = 0; nf < 4; ++nf) {
        int col = (wc << 6) + (nf << 4) + l15;
        b[nf] = *(const v8bf*)((const char*)Bs + col * 128 + slot * 16);
      }
#pragma unroll
      for (int mf = 0; mf < 4; ++mf)
#pragma unroll
        for (int nf = 0; nf < 4; ++nf)
          acc[mf][nf] = __builtin_amdgcn_mfma_f32_16x16x32_bf16(
              a[mf], b[nf], acc[mf][nf], 0, 0, 0);
    }
  }

  // --- fused epilogue: r[row, e] = sqrt( sum_{k<64} C[row, e*64+k]^2 ) ---
  // C/D layout (m89/m91-verified): col = lane&15, row = (lane>>4)*4 + reg.
  // Wave (wr,wc) quadrant covers rows wr*64..+63, cols wc*64..+63 = expert
  // bn*2+wc entirely -> reduction is wave-local (over nf and the 16 cols).
  const int e = (bn << 1) + wc;
#pragma unroll
  for (int mf = 0; mf < 4; ++mf) {
#pragma unroll
    for (int reg = 0; reg < 4; ++reg) {
      float t = 0.f;
#pragma unroll
      for (int nf = 0; nf < 4; ++nf) {
        float v = acc[mf][nf][reg];
        t = fmaf(v, v, t);
      }
      t += __shfl_xor(t, 1);
      t += __shfl_xor(t, 2);
      t += __shfl_xor(t, 4);
      t += __shfl_xor(t, 8);
      if (l15 == 0) {
        int row = (bm << 7) + (wr << 6) + (mf << 4) + (lg << 2) + reg;
        out[(size_t)row * Edim + e] = sqrtf(t);
      }
    }
  }
}

// ---------------------------------------------------------------------------
// Fallback (only if ws is too small for the bf16 hi/lo arrays): plain fp32,
// correct but slow.  One block per b-row.
// ---------------------------------------------------------------------------
__global__ void router_naive(const float* __restrict__ x,
                             const float* __restrict__ w,
                             float* __restrict__ out) {
  int b = blockIdx.x;
  __shared__ float xs[Ddim];
  for (int d = threadIdx.x; d < Ddim; d += 256) xs[d] = x[(size_t)b * Ddim + d];
  __syncthreads();
  int n0 = threadIdx.x * 4;         // 4 consecutive n per thread, same expert
  const float* wrow = w + (size_t)n0 * Ddim;
  float acc[4] = {0.f, 0.f, 0.f, 0.f};
  for (int d = 0; d < Ddim; ++d) {
    float xv = xs[d];
#pragma unroll
    for (int j = 0; j < 4; ++j) acc[j] = fmaf(xv, wrow[(size_t)j * Ddim + d], acc[j]);
  }
  float p = acc[0] * acc[0] + acc[1] * acc[1] + acc[2] * acc[2] + acc[3] * acc[3];
  p += __shfl_xor(p, 1);
  p += __shfl_xor(p, 2);
  p += __shfl_xor(p, 4);
  p += __shfl_xor(p, 8);
  if ((threadIdx.x & 15) == 0)
    out[(size_t)b * Edim + (threadIdx.x >> 4)] = sqrtf(p);
}

extern "C" void kernel_launch(void* const* d_in, const int* in_sizes, int n_in,
                              void* d_out, int out_size, void* d_ws,
                              size_t ws_size, hipStream_t stream) {
  const float* x = (const float*)d_in[0];
  const float* w = (const float*)d_in[1];
  float* out = (float*)d_out;

  const size_t xp_elems = (size_t)Bdim * Kp;   // 67.1M bf16
  const size_t wp_elems = (size_t)Ndim * Kp;   // 8.4M bf16
  const size_t need = (xp_elems + wp_elems) * sizeof(__bf16);  // ~151 MB

  if (ws_size >= need) {
    __bf16* Xp = (__bf16*)d_ws;
    __bf16* Wp = Xp + xp_elems;
    cvt_hilo<<<2048, 256, 0, stream>>>(x, Xp, Bdim * Ddim / 4);
    cvt_hilo<<<1024, 256, 0, stream>>>(w, Wp, Ndim * Ddim / 4);
    gemm_router<<<(Bdim / 128) * (Ndim / 128), 256, 0, stream>>>(Xp, Wp, out);
  } else {
    router_naive<<<Bdim, 256, 0, stream>>>(x, w, out);
  }
}

// Round 2
// 286.483 us; speedup vs baseline: 1.3563x; 1.3563x over previous
//
#include <hip/hip_runtime.h>
#include <hip/hip_bf16.h>

// Router: r[b,e] = || weights[e] @ x[b] ||_2
//   x: [8192, 4096] f32, weights: [16, 64, 4096] f32 -> out: [8192, 16] f32
//
// Round-2 structure:
//   1. cvt_bf16: pure-integer RNE f32->bf16 pack (uint4 in, uint2 out).
//      (Round-1 post-mortem: hi/lo same-k interleave never produced the
//      cross terms, so accuracy was already plain-bf16; the lo half was
//      dead work. absmax 0.0625 == bf16 accuracy, and it passed.)
//   2. gemm_router: m97-structure 128x128 bf16 MFMA GEMM (verified R1:
//      776 TF, 0 bank conflicts), K=4096, fused per-expert L2-norm epilogue.

constexpr int Bdim = 8192;
constexpr int Ddim = 4096;
constexpr int Edim = 16;
constexpr int Kr   = 64;
constexpr int Ndim = Edim * Kr;     // 1024
constexpr int Kp   = Ddim;          // 4096 (plain bf16)

typedef __bf16 v8bf __attribute__((ext_vector_type(8)));
typedef float  v4f  __attribute__((ext_vector_type(4)));

// ---------------------------------------------------------------------------
// f32 -> bf16 RNE, pure integer: bf16(u) = (u + 0x7fff + ((u>>16)&1)) >> 16.
// Each thread: one uint4 load (4 f32, 16B) -> one uint2 store (4 bf16, 8B).
// Both perfectly lane-contiguous.
// ---------------------------------------------------------------------------
__device__ __forceinline__ unsigned rne2(unsigned lo, unsigned hi) {
  unsigned a = (lo + 0x7fffu + ((lo >> 16) & 1u)) >> 16;
  unsigned b = (hi + 0x7fffu + ((hi >> 16) & 1u)) & 0xffff0000u;
  return a | b;
}

__global__ void cvt_bf16(const uint4* __restrict__ in, uint2* __restrict__ out,
                         int n4) {
  int i = blockIdx.x * blockDim.x + threadIdx.x;
  int stride = gridDim.x * blockDim.x;
#pragma unroll 2
  for (; i < n4; i += stride) {
    uint4 v = in[i];
    uint2 r;
    r.x = rne2(v.x, v.y);
    r.y = rne2(v.z, v.w);
    out[i] = r;
  }
}

// ---------------------------------------------------------------------------
// async global->LDS, 16B per lane; LDS dest is wave-uniform base + lane*16.
// ---------------------------------------------------------------------------
__device__ __forceinline__ void gload_lds16(const void* gsrc, void* ldst) {
  __builtin_amdgcn_global_load_lds(
      (const __attribute__((address_space(1))) unsigned int*)gsrc,
      (__attribute__((address_space(3))) unsigned int*)ldst, 16, 0, 0);
}

// ---------------------------------------------------------------------------
// GEMM + fused router epilogue.  m97 structure: 128x128 tile, BK=64, 4 waves
// (2x2), single LDS buffer, 2 barriers per K-step, global_load_lds width 16.
// LDS 16B-slot XOR swizzle (slot ^= row&7): linear LDS dest, pre-swizzled
// global source, swizzled read (both-sides rule 21).  Verified R1: passed,
// 0 bank conflicts.
// ---------------------------------------------------------------------------
__global__ __launch_bounds__(256, 2)
void gemm_router(const __bf16* __restrict__ Xp,  // [8192][4096]
                 const __bf16* __restrict__ Wp,  // [1024][4096]
                 float* __restrict__ out) {      // [8192][16]
  __shared__ __bf16 As[128 * 64];  // 16 KB, row stride 128 B (8 slots x 16 B)
  __shared__ __bf16 Bs[128 * 64];  // 16 KB

  const int bid = blockIdx.x;       // 512 blocks: n fastest -> XCD = bn
  const int bm = bid >> 3;          // 0..63
  const int bn = bid & 7;           // 0..7
  const int tid  = threadIdx.x;
  const int lane = tid & 63;
  const int wid  = tid >> 6;        // 4 waves
  const int wr   = wid >> 1;        // wave row (0..1) -> 64 rows
  const int wc   = wid & 1;         // wave col (0..1) -> 64 cols = 1 expert
  const int l15  = lane & 15;
  const int lg   = lane >> 4;       // 16-lane group = k-group

  v4f acc[4][4] = {};               // 64 VGPRs accumulator

  // --- staging addresses (fixed per thread; add k0 each step) ---
  // chunk c: wave covers LDS rows [wid*32 + c*8, +8), lane -> (row=lane>>3,
  // slot=lane&7).  Source k-slot = slot ^ (row&7)  (row&7 == lane>>3 here).
  const int lr = lane >> 3;
  const int ls = lane & 7;
  const int ss = ls ^ lr;           // swizzled source slot
  const __bf16* pA[4];
  const __bf16* pB[4];
  char* ldsA[4];
  char* ldsB[4];
#pragma unroll
  for (int c = 0; c < 4; ++c) {
    int row = wid * 32 + c * 8 + lr;
    pA[c] = Xp + (size_t)(bm * 128 + row) * Kp + ss * 8;
    pB[c] = Wp + (size_t)(bn * 128 + row) * Kp + ss * 8;
    ldsA[c] = (char*)As + (wid * 4 + c) * 1024;
    ldsB[c] = (char*)Bs + (wid * 4 + c) * 1024;
  }

  for (int k0 = 0; k0 < Kp; k0 += 64) {
    __syncthreads();                 // prev iter done reading LDS
#pragma unroll
    for (int c = 0; c < 4; ++c) gload_lds16(pA[c] + k0, ldsA[c]);
#pragma unroll
    for (int c = 0; c < 4; ++c) gload_lds16(pB[c] + k0, ldsB[c]);
    __syncthreads();                 // compiler drains vmcnt before barrier

#pragma unroll
    for (int kk = 0; kk < 2; ++kk) {
      const int slot = ((kk << 2) + lg) ^ (lane & 7);
      v8bf a[4], b[4];
#pragma unroll
      for (int mf = 0; mf < 4; ++mf) {
        int row = (wr << 6) + (mf << 4) + l15;
        a[mf] = *(const v8bf*)((const char*)As + row * 128 + slot * 16);
      }
#pragma unroll
      for (int nf = 0; nf < 4; ++nf) {
        int col = (wc << 6) + (nf << 4) + l15;
        b[nf] = *(const v8bf*)((const char*)Bs + col * 128 + slot * 16);
      }
#pragma unroll
      for (int mf = 0; mf < 4; ++mf)
#pragma unroll
        for (int nf = 0; nf < 4; ++nf)
          acc[mf][nf] = __builtin_amdgcn_mfma_f32_16x16x32_bf16(
              a[mf], b[nf], acc[mf][nf], 0, 0, 0);
    }
  }

  // --- fused epilogue: r[row, e] = sqrt( sum_{k<64} C[row, e*64+k]^2 ) ---
  // C/D layout (m89/m91-verified): col = lane&15, row = (lane>>4)*4 + reg.
  // Wave (wr,wc) quadrant covers rows wr*64..+63, cols wc*64..+63 = expert
  // bn*2+wc entirely -> reduction is wave-local (over nf and the 16 cols).
  const int e = (bn << 1) + wc;
#pragma unroll
  for (int mf = 0; mf < 4; ++mf) {
#pragma unroll
    for (int reg = 0; reg < 4; ++reg) {
      float t = 0.f;
#pragma unroll
      for (int nf = 0; nf < 4; ++nf) {
        float v = acc[mf][nf][reg];
        t = fmaf(v, v, t);
      }
      t += __shfl_xor(t, 1);
      t += __shfl_xor(t, 2);
      t += __shfl_xor(t, 4);
      t += __shfl_xor(t, 8);
      if (l15 == 0) {
        int row = (bm << 7) + (wr << 6) + (mf << 4) + (lg << 2) + reg;
        out[(size_t)row * Edim + e] = sqrtf(t);
      }
    }
  }
}

// ---------------------------------------------------------------------------
// Fallback (only if ws is too small for the bf16 arrays): plain fp32,
// correct but slow.  One block per b-row.
// ---------------------------------------------------------------------------
__global__ void router_naive(const float* __restrict__ x,
                             const float* __restrict__ w,
                             float* __restrict__ out) {
  int b = blockIdx.x;
  __shared__ float xs[Ddim];
  for (int d = threadIdx.x; d < Ddim; d += 256) xs[d] = x[(size_t)b * Ddim + d];
  __syncthreads();
  int n0 = threadIdx.x * 4;         // 4 consecutive n per thread, same expert
  const float* wrow = w + (size_t)n0 * Ddim;
  float acc[4] = {0.f, 0.f, 0.f, 0.f};
  for (int d = 0; d < Ddim; ++d) {
    float xv = xs[d];
#pragma unroll
    for (int j = 0; j < 4; ++j) acc[j] = fmaf(xv, wrow[(size_t)j * Ddim + d], acc[j]);
  }
  float p = acc[0] * acc[0] + acc[1] * acc[1] + acc[2] * acc[2] + acc[3] * acc[3];
  p += __shfl_xor(p, 1);
  p += __shfl_xor(p, 2);
  p += __shfl_xor(p, 4);
  p += __shfl_xor(p, 8);
  if ((threadIdx.x & 15) == 0)
    out[(size_t)b * Edim + (threadIdx.x >> 4)] = sqrtf(p);
}

extern "C" void kernel_launch(void* const* d_in, const int* in_sizes, int n_in,
                              void* d_out, int out_size, void* d_ws,
                              size_t ws_size, hipStream_t stream) {
  const float* x = (const float*)d_in[0];
  const float* w = (const float*)d_in[1];
  float* out = (float*)d_out;

  const size_t xp_elems = (size_t)Bdim * Kp;   // 33.5M bf16 (67 MB)
  const size_t wp_elems = (size_t)Ndim * Kp;   // 4.2M bf16 (8.4 MB)
  const size_t need = (xp_elems + wp_elems) * sizeof(__bf16);  // ~76 MB

  if (ws_size >= need) {
    __bf16* Xp = (__bf16*)d_ws;
    __bf16* Wp = Xp + xp_elems;
    cvt_bf16<<<2048, 256, 0, stream>>>((const uint4*)x, (uint2*)Xp,
                                       Bdim * Ddim / 4);
    cvt_bf16<<<512, 256, 0, stream>>>((const uint4*)w, (uint2*)Wp,
                                      Ndim * Ddim / 4);
    gemm_router<<<(Bdim / 128) * (Ndim / 128), 256, 0, stream>>>(Xp, Wp, out);
  } else {
    router_naive<<<Bdim, 256, 0, stream>>>(x, w, out);
  }
}